// Round 1
// baseline (2586.636 us; speedup 1.0000x reference)
//
#include <hip/hip_runtime.h>

#define BN_EPS 1e-5f

// ---------------- ws layout (float offsets) ----------------
constexpr size_t SUMS = 0;                        // 8 floats (padded 32)
constexpr size_t W1R  = 32;                       // [ci=1][co=32][9]     = 288
constexpr size_t W2R  = W1R  + 288;               // [32][64][9]          = 18432
constexpr size_t W3R  = W2R  + 18432;             // [64][128][9]         = 73728
constexpr size_t W4R  = W3R  + 73728;             // [128][128][9]        = 147456
constexpr size_t WF1Q = W4R  + 147456;            // [256][6272]          = 1605632
constexpr size_t WF2Q = WF1Q + 1605632;           // [128][256]           = 32768
constexpr size_t WF3Q = WF2Q + 32768;             // [10][128]            = 1280
constexpr size_t BUFA = WF3Q + 1280;              // a1 / a3: 1024*128*14*14 = 25690112 (a1 = 1024*32*28*28 same size)
constexpr size_t BUFB = BUFA + 25690112ull;       // p2: 1024*64*14*14 = 12845056
constexpr size_t P4O  = BUFB;                     // p4: 1024*128*7*7 = 6422528 (overwrites p2 region after conv3)
constexpr size_t F1O  = BUFB + 6422528ull;        // f1: 1024*256
constexpr size_t F2O  = F1O + 262144ull;          // f2: 1024*128

// ---------------- ternarization ----------------
__global__ void zero_sums(float* s) {
    if (threadIdx.x < 8) s[threadIdx.x] = 0.f;
}

__global__ void absmean_reduce(const float* __restrict__ w, int n4, float* __restrict__ sum) {
    __shared__ float sm[256];
    float s = 0.f;
    for (int i = blockIdx.x * blockDim.x + threadIdx.x; i < n4; i += gridDim.x * blockDim.x) {
        float4 v = ((const float4*)w)[i];
        s += fabsf(v.x) + fabsf(v.y) + fabsf(v.z) + fabsf(v.w);
    }
    sm[threadIdx.x] = s;
    __syncthreads();
    for (int o = 128; o > 0; o >>= 1) {
        if (threadIdx.x < o) sm[threadIdx.x] += sm[threadIdx.x + o];
        __syncthreads();
    }
    if (threadIdx.x == 0) atomicAdd(sum, sm[0]);
}

// conv weights: src [co][ci][3][3] -> dst [ci][co][9] quantized
__global__ void tern_conv(const float* __restrict__ w, const float* __restrict__ sum,
                          float* __restrict__ wr, int COUT, int CIN) {
    int N = COUT * CIN * 9;
    float d = 0.7f * (*sum) / (float)N;
    for (int i = blockIdx.x * blockDim.x + threadIdx.x; i < N; i += gridDim.x * blockDim.x) {
        float x = w[i];
        float q = (fabsf(x) > d) ? (x > 0.f ? 1.f : -1.f) : 0.f;
        int co = i / (CIN * 9), r = i % (CIN * 9);
        int ci = r / 9, tap = r % 9;
        wr[((size_t)ci * COUT + co) * 9 + tap] = q;
    }
}

// fc weights: in-place layout [n][k] quantized
__global__ void tern_fc(const float* __restrict__ w, const float* __restrict__ sum,
                        float* __restrict__ wq, int N) {
    float d = 0.7f * (*sum) / (float)N;
    for (int i = blockIdx.x * blockDim.x + threadIdx.x; i < N; i += gridDim.x * blockDim.x) {
        float x = w[i];
        wq[i] = (fabsf(x) > d) ? (x > 0.f ? 1.f : -1.f) : 0.f;
    }
}

// ---------------- direct conv + bias + BN + ReLU (+ optional fused 2x2 maxpool) ----------------
// Block: (COBLK/16) waves; wave w handles output channels [coB0 + 16w, +16).
// Lane<49 owns a 2x2 output-pixel quad of a 14x14 spatial tile (quad == pool window).
template<int CIN, int CITILE, int COUT, int COBLK, int H, bool POOL>
__global__ __launch_bounds__((COBLK / 16) * 64)
void conv_bn_relu(const float* __restrict__ in, const float* __restrict__ wr,
                  const float* __restrict__ bias, const float* __restrict__ gam,
                  const float* __restrict__ bet, const float* __restrict__ mu,
                  const float* __restrict__ var, float* __restrict__ out) {
    constexpr int W   = H;
    constexpr int SPT = H / 14;
    constexpr int BS  = (COBLK / 16) * 64;

    const int tid  = threadIdx.x;
    const int wave = tid >> 6, lane = tid & 63;
    const int sp   = blockIdx.x;
    const int ty0  = (sp / SPT) * 14, tx0 = (sp % SPT) * 14;
    const int coB0 = blockIdx.y * COBLK;
    const int n    = blockIdx.z;

    __shared__ float xs[CITILE][16][17];
    __shared__ __align__(16) float wsh[CITILE * COBLK * 12];

    const bool active = lane < 49;
    const int qy = lane / 7, qx = lane % 7;

    float acc[16][4];
#pragma unroll
    for (int j = 0; j < 16; ++j)
#pragma unroll
        for (int p = 0; p < 4; ++p) acc[j][p] = 0.f;

    for (int ct = 0; ct < CIN / CITILE; ++ct) {
        const int ci0 = ct * CITILE;
        // stage input tile with halo (zero-padded SAME)
        for (int i = tid; i < CITILE * 256; i += BS) {
            int c = i >> 8, p = i & 255, ly = p >> 4, lx = p & 15;
            int gy = ty0 + ly - 1, gx = tx0 + lx - 1;
            float v = 0.f;
            if (gy >= 0 && gy < H && gx >= 0 && gx < W)
                v = in[(((size_t)n * CIN + ci0 + c) * H + gy) * W + gx];
            xs[c][ly][lx] = v;
        }
        // stage weights: src [ci][co][9] contiguous slice -> LDS [ciL][co][12] (padded for b128)
        for (int i = tid; i < CITILE * COBLK * 9; i += BS) {
            int c = i / (COBLK * 9), r = i % (COBLK * 9);
            int co = r / 9, tap = r % 9;
            wsh[(c * COBLK + co) * 12 + tap] =
                wr[((size_t)(ci0 + c) * COUT + coB0 + co) * 9 + tap];
        }
        __syncthreads();
        if (active) {
            for (int c = 0; c < CITILE; ++c) {
                float xv[4][4];
#pragma unroll
                for (int r = 0; r < 4; ++r)
#pragma unroll
                    for (int cc = 0; cc < 4; ++cc)
                        xv[r][cc] = xs[c][2 * qy + r][2 * qx + cc];
#pragma unroll
                for (int j = 0; j < 16; ++j) {
                    const int co = wave * 16 + j;
                    const float* wp = &wsh[(c * COBLK + co) * 12];
                    float4 wa = *(const float4*)wp;
                    float4 wb = *(const float4*)(wp + 4);
                    float w8 = wp[8];
                    float wv[9] = {wa.x, wa.y, wa.z, wa.w, wb.x, wb.y, wb.z, wb.w, w8};
#pragma unroll
                    for (int dy = 0; dy < 3; ++dy)
#pragma unroll
                        for (int dx = 0; dx < 3; ++dx) {
                            float wt = wv[dy * 3 + dx];
                            acc[j][0] += wt * xv[0 + dy][0 + dx];
                            acc[j][1] += wt * xv[0 + dy][1 + dx];
                            acc[j][2] += wt * xv[1 + dy][0 + dx];
                            acc[j][3] += wt * xv[1 + dy][1 + dx];
                        }
                }
            }
        }
        __syncthreads();
    }
    if (!active) return;

    if (POOL) {
        constexpr int Ho = H / 2;
        const int oy = (ty0 >> 1) + qy, ox = (tx0 >> 1) + qx;
#pragma unroll
        for (int j = 0; j < 16; ++j) {
            int co = coB0 + wave * 16 + j;
            float sc = gam[co] * rsqrtf(var[co] + BN_EPS);
            float of = bias[co] - mu[co];
            float bt = bet[co];
            float v0 = (acc[j][0] + of) * sc + bt;
            float v1 = (acc[j][1] + of) * sc + bt;
            float v2 = (acc[j][2] + of) * sc + bt;
            float v3 = (acc[j][3] + of) * sc + bt;
            float mx = fmaxf(fmaxf(v0, v1), fmaxf(v2, v3));
            out[(((size_t)n * COUT + co) * Ho + oy) * Ho + ox] = fmaxf(mx, 0.f);
        }
    } else {
        const int y0 = ty0 + 2 * qy, x0 = tx0 + 2 * qx;
#pragma unroll
        for (int j = 0; j < 16; ++j) {
            int co = coB0 + wave * 16 + j;
            float sc = gam[co] * rsqrtf(var[co] + BN_EPS);
            float of = bias[co] - mu[co];
            float bt = bet[co];
            size_t base = (((size_t)n * COUT + co) * H + y0) * W + x0;
            out[base]         = fmaxf((acc[j][0] + of) * sc + bt, 0.f);
            out[base + 1]     = fmaxf((acc[j][1] + of) * sc + bt, 0.f);
            out[base + W]     = fmaxf((acc[j][2] + of) * sc + bt, 0.f);
            out[base + W + 1] = fmaxf((acc[j][3] + of) * sc + bt, 0.f);
        }
    }
}

// ---------------- tiled SGEMM (out = A[M,K] * Bw[N,K]^T) + bias + BN + ReLU ----------------
__global__ __launch_bounds__(256)
void gemm_bn_relu(const float* __restrict__ A, const float* __restrict__ Bw,
                  const float* __restrict__ bias, const float* __restrict__ gam,
                  const float* __restrict__ bet, const float* __restrict__ mu,
                  const float* __restrict__ var, float* __restrict__ out,
                  int M, int Nn, int K) {
    __shared__ __align__(16) float As[16][68];
    __shared__ __align__(16) float Bs[16][68];
    const int tid = threadIdx.x;
    const int n0 = blockIdx.x * 64, m0 = blockIdx.y * 64;
    const int tm = tid >> 4, tn = tid & 15;
    const int lr = tid >> 2, lk = (tid & 3) * 4;
    float acc[4][4] = {};

    for (int k0 = 0; k0 < K; k0 += 16) {
        float4 av = *(const float4*)&A[(size_t)(m0 + lr) * K + k0 + lk];
        float4 bv = *(const float4*)&Bw[(size_t)(n0 + lr) * K + k0 + lk];
        As[lk + 0][lr] = av.x; As[lk + 1][lr] = av.y; As[lk + 2][lr] = av.z; As[lk + 3][lr] = av.w;
        Bs[lk + 0][lr] = bv.x; Bs[lk + 1][lr] = bv.y; Bs[lk + 2][lr] = bv.z; Bs[lk + 3][lr] = bv.w;
        __syncthreads();
#pragma unroll
        for (int k = 0; k < 16; ++k) {
            float4 a = *(const float4*)&As[k][tm * 4];
            float4 b = *(const float4*)&Bs[k][tn * 4];
            acc[0][0] += a.x * b.x; acc[0][1] += a.x * b.y; acc[0][2] += a.x * b.z; acc[0][3] += a.x * b.w;
            acc[1][0] += a.y * b.x; acc[1][1] += a.y * b.y; acc[1][2] += a.y * b.z; acc[1][3] += a.y * b.w;
            acc[2][0] += a.z * b.x; acc[2][1] += a.z * b.y; acc[2][2] += a.z * b.z; acc[2][3] += a.z * b.w;
            acc[3][0] += a.w * b.x; acc[3][1] += a.w * b.y; acc[3][2] += a.w * b.z; acc[3][3] += a.w * b.w;
        }
        __syncthreads();
    }
#pragma unroll
    for (int i = 0; i < 4; ++i) {
        int row = m0 + tm * 4 + i;
#pragma unroll
        for (int j = 0; j < 4; ++j) {
            int col = n0 + tn * 4 + j;
            float sc = gam[col] * rsqrtf(var[col] + BN_EPS);
            float v = (acc[i][j] + bias[col] - mu[col]) * sc + bet[col];
            out[(size_t)row * Nn + col] = fmaxf(v, 0.f);
        }
    }
}

// ---------------- fc3: [1024,128] x [10,128]^T + bias ----------------
__global__ __launch_bounds__(256)
void fc3_kernel(const float* __restrict__ A, const float* __restrict__ Bw,
                const float* __restrict__ bias, float* __restrict__ out) {
    int i = blockIdx.x * blockDim.x + threadIdx.x;
    if (i >= 1024 * 10) return;
    int n = i / 10, j = i % 10;
    const float4* a = (const float4*)&A[(size_t)n * 128];
    const float4* b = (const float4*)&Bw[(size_t)j * 128];
    float s = 0.f;
#pragma unroll
    for (int k = 0; k < 32; ++k) {
        float4 x = a[k], y = b[k];
        s += x.x * y.x + x.y * y.y + x.z * y.z + x.w * y.w;
    }
    out[i] = s + bias[j];
}

extern "C" void kernel_launch(void* const* d_in, const int* in_sizes, int n_in,
                              void* d_out, int out_size, void* d_ws, size_t ws_size,
                              hipStream_t stream) {
    (void)in_sizes; (void)n_in; (void)out_size; (void)ws_size;
    const float* x   = (const float*)d_in[0];
    const float* w1  = (const float*)d_in[1];
    const float* w2  = (const float*)d_in[2];
    const float* w3  = (const float*)d_in[3];
    const float* w4  = (const float*)d_in[4];
    const float* wf1 = (const float*)d_in[5];
    const float* wf2 = (const float*)d_in[6];
    const float* wf3 = (const float*)d_in[7];
    auto P = [&](int i) { return (const float*)d_in[i]; };
    float* ws = (float*)d_ws;
    float* sums = ws + SUMS;

    // ternarize all 7 weights
    zero_sums<<<1, 64, 0, stream>>>(sums);
    auto red = [&](const float* w, int N, int idx) {
        int n4 = N / 4;
        int nb = (n4 + 255) / 256; if (nb > 256) nb = 256;
        absmean_reduce<<<nb, 256, 0, stream>>>(w, n4, sums + idx);
    };
    red(w1, 288, 0);      red(w2, 18432, 1);  red(w3, 73728, 2); red(w4, 147456, 3);
    red(wf1, 1605632, 4); red(wf2, 32768, 5); red(wf3, 1280, 6);

    tern_conv<<<(288    + 255) / 256, 256, 0, stream>>>(w1, sums + 0, ws + W1R, 32, 1);
    tern_conv<<<(18432  + 255) / 256, 256, 0, stream>>>(w2, sums + 1, ws + W2R, 64, 32);
    tern_conv<<<(73728  + 255) / 256, 256, 0, stream>>>(w3, sums + 2, ws + W3R, 128, 64);
    tern_conv<<<(147456 + 255) / 256, 256, 0, stream>>>(w4, sums + 3, ws + W4R, 128, 128);
    tern_fc<<<1024, 256, 0, stream>>>(wf1, sums + 4, ws + WF1Q, 1605632);
    tern_fc<<<128,  256, 0, stream>>>(wf2, sums + 5, ws + WF2Q, 32768);
    tern_fc<<<8,    256, 0, stream>>>(wf3, sums + 6, ws + WF3Q, 1280);

    // conv1: [1024,1,28,28] -> a1 [1024,32,28,28]
    conv_bn_relu<1, 1, 32, 32, 28, false><<<dim3(4, 1, 1024), 128, 0, stream>>>(
        x, ws + W1R, P(8), P(9), P(10), P(11), P(12), ws + BUFA);
    // conv2 + pool: a1 -> p2 [1024,64,14,14]
    conv_bn_relu<32, 8, 64, 64, 28, true><<<dim3(4, 1, 1024), 256, 0, stream>>>(
        ws + BUFA, ws + W2R, P(13), P(14), P(15), P(16), P(17), ws + BUFB);
    // conv3: p2 -> a3 [1024,128,14,14]
    conv_bn_relu<64, 8, 128, 64, 14, false><<<dim3(1, 2, 1024), 256, 0, stream>>>(
        ws + BUFB, ws + W3R, P(18), P(19), P(20), P(21), P(22), ws + BUFA);
    // conv4 + pool: a3 -> p4 [1024,128,7,7]
    conv_bn_relu<128, 8, 128, 64, 14, true><<<dim3(1, 2, 1024), 256, 0, stream>>>(
        ws + BUFA, ws + W4R, P(23), P(24), P(25), P(26), P(27), ws + P4O);
    // fc1: p4 (flat [1024,6272]) -> f1 [1024,256]
    gemm_bn_relu<<<dim3(4, 16), 256, 0, stream>>>(
        ws + P4O, ws + WF1Q, P(28), P(29), P(30), P(31), P(32), ws + F1O, 1024, 256, 6272);
    // fc2: f1 -> f2 [1024,128]
    gemm_bn_relu<<<dim3(2, 16), 256, 0, stream>>>(
        ws + F1O, ws + WF2Q, P(33), P(34), P(35), P(36), P(37), ws + F2O, 1024, 128, 256);
    // fc3: f2 -> logits [1024,10]
    fc3_kernel<<<40, 256, 0, stream>>>(ws + F2O, ws + WF3Q, P(38), (float*)d_out);
}

// Round 2
// 537.509 us; speedup vs baseline: 4.8123x; 4.8123x over previous
//
#include <hip/hip_runtime.h>
#include <hip/hip_bf16.h>

#define BN_EPS 1e-5f

typedef __attribute__((ext_vector_type(8))) short bf16x8;
typedef __attribute__((ext_vector_type(4))) float f32x4;
typedef unsigned short u16;
typedef unsigned int u32;

__device__ __forceinline__ void load16(const void* g, void* l) {
    __builtin_amdgcn_global_load_lds((const __attribute__((address_space(1))) void*)g,
                                     (__attribute__((address_space(3))) void*)l, 16, 0, 0);
}
__device__ __forceinline__ u16 f2b(float v) {
    __hip_bfloat16 h = __float2bfloat16(v);
    return *reinterpret_cast<u16*>(&h);
}

// ---------------- ws layout (BYTE offsets) ----------------
constexpr size_t ALGN(size_t x) { return (x + 255) & ~(size_t)255; }
constexpr size_t O_SUMS = 0;                                   // 8 f32
constexpr size_t O_W1R  = 256;                                 // 288 f32
constexpr size_t O_WF2Q = ALGN(O_W1R + 288 * 4);               // 32768 f32
constexpr size_t O_WF3Q = ALGN(O_WF2Q + 32768 * 4);            // 1280 f32
constexpr size_t O_BQ2  = ALGN(O_WF3Q + 1280 * 4);             // [64][288] bf16
constexpr size_t O_BQ3  = ALGN(O_BQ2 + 64 * 288 * 2);          // [128][576] bf16
constexpr size_t O_BQ4  = ALGN(O_BQ3 + 128 * 576 * 2);         // [128][1152] bf16
constexpr size_t O_BQF1 = ALGN(O_BQ4 + 128 * 1152 * 2);        // [256][6272] bf16
constexpr size_t O_F1   = ALGN(O_BQF1 + 256 * 6272 * 2);       // [1024][256] f32
constexpr size_t O_F2   = ALGN(O_F1 + 1024 * 256 * 4);         // [1024][128] f32
// arena1: act1 pad30 C=32 (1024*30*30*32) / act4raw (1024*196*128)
constexpr size_t O_A1   = ALGN(O_F2 + 1024 * 128 * 4);
// arena2: act2raw (1024*784*64) / act3 pad16 C=128 (1024*256*128)
constexpr size_t O_A2   = ALGN(O_A1 + (size_t)1024 * 900 * 32 * 2);
// arena3: act2p pad16 C=64 (1024*256*64) / act4p flat (1024*6272)
constexpr size_t O_A3   = ALGN(O_A2 + (size_t)1024 * 784 * 64 * 2);
// total ~200.5 MB

// ---------------- ternarization ----------------
__global__ void zero_sums(float* s) { if (threadIdx.x < 8) s[threadIdx.x] = 0.f; }

__global__ void absmean_reduce(const float* __restrict__ w, int n4, float* __restrict__ sum) {
    __shared__ float sm[256];
    float s = 0.f;
    for (int i = blockIdx.x * blockDim.x + threadIdx.x; i < n4; i += gridDim.x * blockDim.x) {
        float4 v = ((const float4*)w)[i];
        s += fabsf(v.x) + fabsf(v.y) + fabsf(v.z) + fabsf(v.w);
    }
    sm[threadIdx.x] = s;
    __syncthreads();
    for (int o = 128; o > 0; o >>= 1) {
        if (threadIdx.x < o) sm[threadIdx.x] += sm[threadIdx.x + o];
        __syncthreads();
    }
    if (threadIdx.x == 0) atomicAdd(sum, sm[0]);
}

// conv weights: src [co][ci][9] -> dst bf16 [co][tap*CIN+ci]
__global__ void tern_conv_bf16(const float* __restrict__ w, const float* __restrict__ sum,
                               u16* __restrict__ bq, int COUT, int CIN) {
    int N = COUT * CIN * 9;
    float d = 0.7f * (*sum) / (float)N;
    for (int i = blockIdx.x * blockDim.x + threadIdx.x; i < N; i += gridDim.x * blockDim.x) {
        float v = w[i];
        float q = (fabsf(v) > d) ? (v > 0.f ? 1.f : -1.f) : 0.f;
        int co = i / (CIN * 9), r = i % (CIN * 9);
        int ci = r / 9, tap = r % 9;
        bq[(size_t)co * CIN * 9 + tap * CIN + ci] = f2b(q);
    }
}

// fc weights f32 in-place layout (also used for w1)
__global__ void tern_fc(const float* __restrict__ w, const float* __restrict__ sum,
                        float* __restrict__ wq, int N) {
    float d = 0.7f * (*sum) / (float)N;
    for (int i = blockIdx.x * blockDim.x + threadIdx.x; i < N; i += gridDim.x * blockDim.x) {
        float x = w[i];
        wq[i] = (fabsf(x) > d) ? (x > 0.f ? 1.f : -1.f) : 0.f;
    }
}

// wf1 [256][6272] k=c*49+s -> bf16 [256][s*128+c] (match NHWC flatten)
__global__ void tern_fc1_bf16(const float* __restrict__ w, const float* __restrict__ sum,
                              u16* __restrict__ bq) {
    const int N = 256 * 6272;
    float d = 0.7f * (*sum) / (float)N;
    for (int i = blockIdx.x * blockDim.x + threadIdx.x; i < N; i += gridDim.x * blockDim.x) {
        float v = w[i];
        float q = (fabsf(v) > d) ? (v > 0.f ? 1.f : -1.f) : 0.f;
        int j = i / 6272, k = i % 6272;
        int c = k / 49, s = k % 49;
        bq[(size_t)j * 6272 + s * 128 + c] = f2b(q);
    }
}

// ---------------- conv1 direct (Cin=1) -> pad30 NHWC bf16 ----------------
__global__ __launch_bounds__(256)
void conv1_direct(const float* __restrict__ x, const float* __restrict__ w1r,
                  const float* __restrict__ bias, const float* __restrict__ gam,
                  const float* __restrict__ bet, const float* __restrict__ mu,
                  const float* __restrict__ var, u16* __restrict__ out) {
    __shared__ float xs[784];
    __shared__ float wsh[288];
    __shared__ float scl[32], sft[32];
    const int n = blockIdx.x, tid = threadIdx.x;
    for (int i = tid; i < 784; i += 256) xs[i] = x[(size_t)n * 784 + i];
    for (int i = tid; i < 288; i += 256) wsh[i] = w1r[i];
    if (tid < 32) {
        float s = gam[tid] * rsqrtf(var[tid] + BN_EPS);
        scl[tid] = s;
        sft[tid] = (bias[tid] - mu[tid]) * s + bet[tid];
    }
    __syncthreads();
    for (int p = tid; p < 784; p += 256) {
        int y = p / 28, xx = p % 28;
        float patch[9];
#pragma unroll
        for (int dy = 0; dy < 3; ++dy)
#pragma unroll
            for (int dx = 0; dx < 3; ++dx) {
                int gy = y + dy - 1, gx = xx + dx - 1;
                patch[dy * 3 + dx] = (gy >= 0 && gy < 28 && gx >= 0 && gx < 28) ? xs[gy * 28 + gx] : 0.f;
            }
        u32 pk[16];
#pragma unroll
        for (int co = 0; co < 32; co += 2) {
            float s0 = 0.f, s1 = 0.f;
#pragma unroll
            for (int t = 0; t < 9; ++t) {
                s0 += wsh[co * 9 + t] * patch[t];
                s1 += wsh[(co + 1) * 9 + t] * patch[t];
            }
            float v0 = fmaxf(s0 * scl[co] + sft[co], 0.f);
            float v1 = fmaxf(s1 * scl[co + 1] + sft[co + 1], 0.f);
            pk[co >> 1] = ((u32)f2b(v1) << 16) | (u32)f2b(v0);
        }
        size_t base = ((size_t)(n * 30 + y + 1) * 30 + (xx + 1)) * 32;
#pragma unroll
        for (int q = 0; q < 4; ++q) ((uint4*)(out + base))[q] = ((uint4*)pk)[q];
    }
}

// ---------------- border zero for padded NHWC buffers ----------------
template<int C, int HP, int HV>
__global__ void border_zero(u16* __restrict__ buf) {
    constexpr int NB = 2 * HP + 2 * HV;
    constexpr int CG = C / 8;
    int i = blockIdx.x * blockDim.x + threadIdx.x;
    if (i >= 1024 * NB * CG) return;
    int cg = i % CG, r = i / CG;
    int b = r % NB, n = r / NB;
    int py, px;
    if (b < HP)            { py = 0;               px = b; }
    else if (b < 2 * HP)   { py = HP - 1;          px = b - HP; }
    else if (b < 2 * HP + HV) { py = b - 2 * HP + 1;  px = 0; }
    else                   { py = b - 2 * HP - HV + 1; px = HP - 1; }
    size_t off = ((size_t)(n * HP + py) * HP + px) * C + cg * 8;
    *(uint4*)(buf + off) = make_uint4(0, 0, 0, 0);
}

// ---------------- implicit-GEMM conv, bf16 MFMA 16x16x32 ----------------
// A: NHWC padded input act[n][HP][HP][CIN]; B: bq[co][tap*CIN+ci] bf16
// M = 1024*HV*HV (m = n*HV*HV + y*HV + x), N = COUT, K = 9*CIN
// OM==0: out raw [m][COUT]; OM==1: out pad16 interior ((n*16+y+1)*16+x+1)*COUT
template<int CIN, int COUT, int HV, int HP, int OM>
__global__ __launch_bounds__(256)
void convgemm(const u16* __restrict__ act, const u16* __restrict__ bq,
              const float* __restrict__ bias, const float* __restrict__ gam,
              const float* __restrict__ bet, const float* __restrict__ mu,
              const float* __restrict__ var, u16* __restrict__ out) {
    constexpr int BN = COUT;                   // 64 or 128
    constexpr int BM = (BN == 64) ? 256 : 128; // block rows
    constexpr int K = 9 * CIN;
    constexpr int STEPS = K / 32;
    constexpr int TPC = CIN / 32;              // k-steps per tap
    constexpr int WM = (BN == 64) ? 4 : 2;     // wave grid
    constexpr int RA = BM / 64;                // A staging rounds
    constexpr int RB = BN / 64;                // B staging rounds

    __shared__ __align__(16) u16 Alds[BM * 32];
    __shared__ __align__(16) u16 Blds[BN * 32];
    __shared__ int rowbaseA[BM];
    __shared__ int rowbaseO[BM];
    __shared__ float scl[BN], sft[BN];

    const int tid = threadIdx.x;
    const int m0 = blockIdx.x * BM;

    for (int t = tid; t < BM; t += 256) {
        int m = m0 + t;
        int n = m / (HV * HV), r = m % (HV * HV);
        int y = r / HV, x = r % HV;
        rowbaseA[t] = ((n * HP + y) * HP + x) * CIN;
        rowbaseO[t] = (OM == 0) ? m * COUT : ((n * 16 + y + 1) * 16 + (x + 1)) * COUT;
    }
    if (tid < BN) {
        float s = gam[tid] * rsqrtf(var[tid] + BN_EPS);
        scl[tid] = s;
        sft[tid] = (bias[tid] - mu[tid]) * s + bet[tid];
    }
    __syncthreads();

    int ab[RA];
#pragma unroll
    for (int r = 0; r < RA; ++r) ab[r] = rowbaseA[r * 64 + (tid >> 2)];
    const int achk = (tid & 3) * 16;                 // byte offset within 64B row
    const char* actb = (const char*)act;
    const char* bqb = (const char*)bq;
    const size_t brow0 = (size_t)(tid >> 2) * K * 2; // B row bytes
    char* AB = (char*)Alds;
    char* BB = (char*)Blds;

    const int wave = tid >> 6, lane = tid & 63;
    const int wm = wave % WM, wn = wave / WM;
    const int wtm0 = wm * (BM / WM);                 // 64-row wave tile
    const int wtn0 = wn * 64;
    const int fr = lane & 15;
    const int fk = (lane >> 4) * 16;                 // k-chunk byte offset

    f32x4 acc[4][4] = {};

    for (int s = 0; s < STEPS; ++s) {
        int tap = s / TPC, cio = (s % TPC) * 32;
        int dy = tap / 3, dx = tap % 3;
        int toff = (dy * HP + dx) * CIN + cio;       // element offset
        int abo = toff * 2 + achk;
#pragma unroll
        for (int r = 0; r < RA; ++r)
            load16(actb + (size_t)ab[r] * 2 + abo, AB + r * 4096 + tid * 16);
        int bko = s * 64 + achk;
#pragma unroll
        for (int r = 0; r < RB; ++r)
            load16(bqb + brow0 + (size_t)r * 64 * K * 2 + bko, BB + r * 4096 + tid * 16);
        __syncthreads();

        bf16x8 af[4], bf[4];
#pragma unroll
        for (int mt = 0; mt < 4; ++mt)
            af[mt] = *(const bf16x8*)(AB + (wtm0 + mt * 16 + fr) * 64 + fk);
#pragma unroll
        for (int nt = 0; nt < 4; ++nt)
            bf[nt] = *(const bf16x8*)(BB + (wtn0 + nt * 16 + fr) * 64 + fk);
#pragma unroll
        for (int mt = 0; mt < 4; ++mt)
#pragma unroll
            for (int nt = 0; nt < 4; ++nt)
                acc[mt][nt] = __builtin_amdgcn_mfma_f32_16x16x32_bf16(af[mt], bf[nt], acc[mt][nt], 0, 0, 0);
        __syncthreads();
    }

    // epilogue: C/D map col=lane&15, row=(lane>>4)*4+reg
#pragma unroll
    for (int mt = 0; mt < 4; ++mt) {
        int rb = wtm0 + mt * 16 + (lane >> 4) * 4;
        int ob0 = rowbaseO[rb], ob1 = rowbaseO[rb + 1], ob2 = rowbaseO[rb + 2], ob3 = rowbaseO[rb + 3];
#pragma unroll
        for (int nt = 0; nt < 4; ++nt) {
            int col = wtn0 + nt * 16 + fr;
            float sc = scl[col], sh = sft[col];
            f32x4 a = acc[mt][nt];
            out[(size_t)ob0 + col] = f2b(fmaxf(a[0] * sc + sh, 0.f));
            out[(size_t)ob1 + col] = f2b(fmaxf(a[1] * sc + sh, 0.f));
            out[(size_t)ob2 + col] = f2b(fmaxf(a[2] * sc + sh, 0.f));
            out[(size_t)ob3 + col] = f2b(fmaxf(a[3] * sc + sh, 0.f));
        }
    }
}

// ---------------- pools (bf16 bits are order-preserving for >=0) ----------------
__global__ void pool2(const u16* __restrict__ in, u16* __restrict__ out) {
    int i = blockIdx.x * blockDim.x + threadIdx.x;
    if (i >= 1024 * 256 * 16) return;
    int cg = i & 15, p = (i >> 4) & 255, n = i >> 12;
    int py = p >> 4, px = p & 15;
    ushort4 r = make_ushort4(0, 0, 0, 0);
    if (py >= 1 && py <= 14 && px >= 1 && px <= 14) {
        int y = (py - 1) * 2, x = (px - 1) * 2;
        const u16* b = in + ((size_t)(n * 28 + y) * 28 + x) * 64 + cg * 4;
        ushort4 a0 = *(const ushort4*)(b);
        ushort4 a1 = *(const ushort4*)(b + 64);
        ushort4 a2 = *(const ushort4*)(b + 28 * 64);
        ushort4 a3 = *(const ushort4*)(b + 28 * 64 + 64);
        r.x = max(max((int)a0.x, (int)a1.x), max((int)a2.x, (int)a3.x));
        r.y = max(max((int)a0.y, (int)a1.y), max((int)a2.y, (int)a3.y));
        r.z = max(max((int)a0.z, (int)a1.z), max((int)a2.z, (int)a3.z));
        r.w = max(max((int)a0.w, (int)a1.w), max((int)a2.w, (int)a3.w));
    }
    *(ushort4*)(out + ((size_t)n * 256 + p) * 64 + cg * 4) = r;
}

__global__ void pool4(const u16* __restrict__ in, u16* __restrict__ out) {
    int i = blockIdx.x * blockDim.x + threadIdx.x;
    if (i >= 1024 * 49 * 32) return;
    int cg = i & 31, s = (i >> 5) % 49, n = i / (49 * 32);
    int oy = s / 7, ox = s % 7;
    const u16* b = in + ((size_t)(n * 14 + oy * 2) * 14 + ox * 2) * 128 + cg * 4;
    ushort4 a0 = *(const ushort4*)(b);
    ushort4 a1 = *(const ushort4*)(b + 128);
    ushort4 a2 = *(const ushort4*)(b + 14 * 128);
    ushort4 a3 = *(const ushort4*)(b + 14 * 128 + 128);
    ushort4 r;
    r.x = max(max((int)a0.x, (int)a1.x), max((int)a2.x, (int)a3.x));
    r.y = max(max((int)a0.y, (int)a1.y), max((int)a2.y, (int)a3.y));
    r.z = max(max((int)a0.z, (int)a1.z), max((int)a2.z, (int)a3.z));
    r.w = max(max((int)a0.w, (int)a1.w), max((int)a2.w, (int)a3.w));
    *(ushort4*)(out + ((size_t)n * 49 + s) * 128 + cg * 4) = r;
}

// ---------------- fc1: [1024,6272]bf16 x [256,6272]bf16^T, MFMA, BN+ReLU, f32 out ----------------
__global__ __launch_bounds__(256)
void fc1gemm(const u16* __restrict__ A, const u16* __restrict__ Bq,
             const float* __restrict__ bias, const float* __restrict__ gam,
             const float* __restrict__ bet, const float* __restrict__ mu,
             const float* __restrict__ var, float* __restrict__ out) {
    constexpr int K = 6272, STEPS = K / 32;
    __shared__ __align__(16) u16 Alds[64 * 32];
    __shared__ __align__(16) u16 Blds[128 * 32];
    __shared__ float scl[128], sft[128];
    const int tid = threadIdx.x;
    const int m0 = blockIdx.x * 64, n0 = blockIdx.y * 128;
    if (tid < 128) {
        int g = n0 + tid;
        float s = gam[g] * rsqrtf(var[g] + BN_EPS);
        scl[tid] = s;
        sft[tid] = (bias[g] - mu[g]) * s + bet[g];
    }
    const char* Ab = (const char*)A;
    const char* Bb = (const char*)Bq;
    const size_t arow = (size_t)(m0 + (tid >> 2)) * K * 2;
    const size_t brow = (size_t)(n0 + (tid >> 2)) * K * 2;
    const int achk = (tid & 3) * 16;
    char* AB = (char*)Alds;
    char* BB = (char*)Blds;

    const int wave = tid >> 6, lane = tid & 63;
    const int wm = wave & 1, wn = wave >> 1;
    const int wtm0 = wm * 32, wtn0 = wn * 64;
    const int fr = lane & 15, fk = (lane >> 4) * 16;

    f32x4 acc[2][4] = {};
    __syncthreads();

    for (int s = 0; s < STEPS; ++s) {
        int ko = s * 64 + achk;
        load16(Ab + arow + ko, AB + tid * 16);
        load16(Bb + brow + ko, BB + tid * 16);
        load16(Bb + brow + (size_t)64 * K * 2 + ko, BB + 4096 + tid * 16);
        __syncthreads();
        bf16x8 af[2], bf[4];
#pragma unroll
        for (int mt = 0; mt < 2; ++mt)
            af[mt] = *(const bf16x8*)(AB + (wtm0 + mt * 16 + fr) * 64 + fk);
#pragma unroll
        for (int nt = 0; nt < 4; ++nt)
            bf[nt] = *(const bf16x8*)(BB + (wtn0 + nt * 16 + fr) * 64 + fk);
#pragma unroll
        for (int mt = 0; mt < 2; ++mt)
#pragma unroll
            for (int nt = 0; nt < 4; ++nt)
                acc[mt][nt] = __builtin_amdgcn_mfma_f32_16x16x32_bf16(af[mt], bf[nt], acc[mt][nt], 0, 0, 0);
        __syncthreads();
    }
#pragma unroll
    for (int mt = 0; mt < 2; ++mt) {
        int rb = wtm0 + mt * 16 + (lane >> 4) * 4;
#pragma unroll
        for (int nt = 0; nt < 4; ++nt) {
            int col = wtn0 + nt * 16 + fr;
            float sc = scl[col], sh = sft[col];
            f32x4 a = acc[mt][nt];
#pragma unroll
            for (int j = 0; j < 4; ++j) {
                int grow = m0 + rb + j;
                out[(size_t)grow * 256 + n0 + col] = fmaxf(a[j] * sc + sh, 0.f);
            }
        }
    }
}

// ---------------- fc2 fp32 GEMM + BN + ReLU (K=256) ----------------
__global__ __launch_bounds__(256)
void gemm_bn_relu(const float* __restrict__ A, const float* __restrict__ Bw,
                  const float* __restrict__ bias, const float* __restrict__ gam,
                  const float* __restrict__ bet, const float* __restrict__ mu,
                  const float* __restrict__ var, float* __restrict__ out,
                  int M, int Nn, int K) {
    __shared__ __align__(16) float As[16][68];
    __shared__ __align__(16) float Bs[16][68];
    const int tid = threadIdx.x;
    const int n0 = blockIdx.x * 64, m0 = blockIdx.y * 64;
    const int tm = tid >> 4, tn = tid & 15;
    const int lr = tid >> 2, lk = (tid & 3) * 4;
    float acc[4][4] = {};
    for (int k0 = 0; k0 < K; k0 += 16) {
        float4 av = *(const float4*)&A[(size_t)(m0 + lr) * K + k0 + lk];
        float4 bv = *(const float4*)&Bw[(size_t)(n0 + lr) * K + k0 + lk];
        As[lk + 0][lr] = av.x; As[lk + 1][lr] = av.y; As[lk + 2][lr] = av.z; As[lk + 3][lr] = av.w;
        Bs[lk + 0][lr] = bv.x; Bs[lk + 1][lr] = bv.y; Bs[lk + 2][lr] = bv.z; Bs[lk + 3][lr] = bv.w;
        __syncthreads();
#pragma unroll
        for (int k = 0; k < 16; ++k) {
            float4 a = *(const float4*)&As[k][tm * 4];
            float4 b = *(const float4*)&Bs[k][tn * 4];
            acc[0][0] += a.x * b.x; acc[0][1] += a.x * b.y; acc[0][2] += a.x * b.z; acc[0][3] += a.x * b.w;
            acc[1][0] += a.y * b.x; acc[1][1] += a.y * b.y; acc[1][2] += a.y * b.z; acc[1][3] += a.y * b.w;
            acc[2][0] += a.z * b.x; acc[2][1] += a.z * b.y; acc[2][2] += a.z * b.z; acc[2][3] += a.z * b.w;
            acc[3][0] += a.w * b.x; acc[3][1] += a.w * b.y; acc[3][2] += a.w * b.z; acc[3][3] += a.w * b.w;
        }
        __syncthreads();
    }
#pragma unroll
    for (int i = 0; i < 4; ++i) {
        int row = m0 + tm * 4 + i;
#pragma unroll
        for (int j = 0; j < 4; ++j) {
            int col = n0 + tn * 4 + j;
            float sc = gam[col] * rsqrtf(var[col] + BN_EPS);
            float v = (acc[i][j] + bias[col] - mu[col]) * sc + bet[col];
            out[(size_t)row * Nn + col] = fmaxf(v, 0.f);
        }
    }
}

__global__ __launch_bounds__(256)
void fc3_kernel(const float* __restrict__ A, const float* __restrict__ Bw,
                const float* __restrict__ bias, float* __restrict__ out) {
    int i = blockIdx.x * blockDim.x + threadIdx.x;
    if (i >= 1024 * 10) return;
    int n = i / 10, j = i % 10;
    const float4* a = (const float4*)&A[(size_t)n * 128];
    const float4* b = (const float4*)&Bw[(size_t)j * 128];
    float s = 0.f;
#pragma unroll
    for (int k = 0; k < 32; ++k) {
        float4 x = a[k], y = b[k];
        s += x.x * y.x + x.y * y.y + x.z * y.z + x.w * y.w;
    }
    out[i] = s + bias[j];
}

extern "C" void kernel_launch(void* const* d_in, const int* in_sizes, int n_in,
                              void* d_out, int out_size, void* d_ws, size_t ws_size,
                              hipStream_t stream) {
    (void)in_sizes; (void)n_in; (void)out_size; (void)ws_size;
    const float* x   = (const float*)d_in[0];
    const float* w1  = (const float*)d_in[1];
    const float* w2  = (const float*)d_in[2];
    const float* w3  = (const float*)d_in[3];
    const float* w4  = (const float*)d_in[4];
    const float* wf1 = (const float*)d_in[5];
    const float* wf2 = (const float*)d_in[6];
    const float* wf3 = (const float*)d_in[7];
    auto P = [&](int i) { return (const float*)d_in[i]; };
    char* wsb = (char*)d_ws;
    float* sums = (float*)(wsb + O_SUMS);
    float* w1r  = (float*)(wsb + O_W1R);
    float* wf2q = (float*)(wsb + O_WF2Q);
    float* wf3q = (float*)(wsb + O_WF3Q);
    u16* bq2  = (u16*)(wsb + O_BQ2);
    u16* bq3  = (u16*)(wsb + O_BQ3);
    u16* bq4  = (u16*)(wsb + O_BQ4);
    u16* bqf1 = (u16*)(wsb + O_BQF1);
    float* f1 = (float*)(wsb + O_F1);
    float* f2 = (float*)(wsb + O_F2);
    u16* act1    = (u16*)(wsb + O_A1);   // pad30 C=32
    u16* act4raw = (u16*)(wsb + O_A1);   // [1024*196][128]
    u16* act2raw = (u16*)(wsb + O_A2);   // [1024*784][64]
    u16* act3    = (u16*)(wsb + O_A2);   // pad16 C=128
    u16* act2p   = (u16*)(wsb + O_A3);   // pad16 C=64
    u16* act4p   = (u16*)(wsb + O_A3);   // [1024][6272]

    // ternarize
    zero_sums<<<1, 64, 0, stream>>>(sums);
    auto red = [&](const float* w, int N, int idx) {
        int n4 = N / 4;
        int nb = (n4 + 255) / 256; if (nb > 256) nb = 256;
        absmean_reduce<<<nb, 256, 0, stream>>>(w, n4, sums + idx);
    };
    red(w1, 288, 0);      red(w2, 18432, 1);  red(w3, 73728, 2); red(w4, 147456, 3);
    red(wf1, 1605632, 4); red(wf2, 32768, 5); red(wf3, 1280, 6);

    tern_fc<<<2, 256, 0, stream>>>(w1, sums + 0, w1r, 288);
    tern_conv_bf16<<<(18432 + 255) / 256, 256, 0, stream>>>(w2, sums + 1, bq2, 64, 32);
    tern_conv_bf16<<<(73728 + 255) / 256, 256, 0, stream>>>(w3, sums + 2, bq3, 128, 64);
    tern_conv_bf16<<<(147456 + 255) / 256, 256, 0, stream>>>(w4, sums + 3, bq4, 128, 128);
    tern_fc1_bf16<<<1024, 256, 0, stream>>>(wf1, sums + 4, bqf1);
    tern_fc<<<128, 256, 0, stream>>>(wf2, sums + 5, wf2q, 32768);
    tern_fc<<<8, 256, 0, stream>>>(wf3, sums + 6, wf3q, 1280);

    // conv1 -> act1 (pad30) interior + border zero
    border_zero<32, 30, 28><<<(1024 * 116 * 4 + 255) / 256, 256, 0, stream>>>(act1);
    conv1_direct<<<1024, 256, 0, stream>>>(x, w1r, P(8), P(9), P(10), P(11), P(12), act1);
    // conv2: act1 -> act2raw [m][64]
    convgemm<32, 64, 28, 30, 0><<<3136, 256, 0, stream>>>(
        act1, bq2, P(13), P(14), P(15), P(16), P(17), act2raw);
    // pool2: act2raw -> act2p (pad16 C=64, borders zeroed inline)
    pool2<<<(1024 * 256 * 16 + 255) / 256, 256, 0, stream>>>(act2raw, act2p);
    // border zero for act3 (aliases act2raw region; after pool2)
    border_zero<128, 16, 14><<<(1024 * 60 * 16 + 255) / 256, 256, 0, stream>>>(act3);
    // conv3: act2p -> act3 (pad16 interior)
    convgemm<64, 128, 14, 16, 1><<<1568, 256, 0, stream>>>(
        act2p, bq3, P(18), P(19), P(20), P(21), P(22), act3);
    // conv4: act3 -> act4raw [m][128]
    convgemm<128, 128, 14, 16, 0><<<1568, 256, 0, stream>>>(
        act3, bq4, P(23), P(24), P(25), P(26), P(27), act4raw);
    // pool4: act4raw -> act4p [1024][6272]
    pool4<<<(1024 * 49 * 32 + 255) / 256, 256, 0, stream>>>(act4raw, act4p);
    // fc1 (MFMA) -> f1 [1024][256] f32
    fc1gemm<<<dim3(16, 2), 256, 0, stream>>>(
        act4p, bqf1, P(28), P(29), P(30), P(31), P(32), f1);
    // fc2 (fp32) -> f2
    gemm_bn_relu<<<dim3(2, 16), 256, 0, stream>>>(
        f1, wf2q, P(33), P(34), P(35), P(36), P(37), f2, 1024, 128, 256);
    // fc3 -> logits
    fc3_kernel<<<40, 256, 0, stream>>>(f2, wf3q, P(38), (float*)d_out);
}

// Round 3
// 499.665 us; speedup vs baseline: 5.1767x; 1.0757x over previous
//
#include <hip/hip_runtime.h>
#include <hip/hip_bf16.h>

#define BN_EPS 1e-5f

typedef __attribute__((ext_vector_type(8))) short bf16x8;
typedef __attribute__((ext_vector_type(4))) float f32x4;
typedef unsigned short u16;
typedef unsigned int u32;

__device__ __forceinline__ void load16(const void* g, void* l) {
    __builtin_amdgcn_global_load_lds((const __attribute__((address_space(1))) void*)g,
                                     (__attribute__((address_space(3))) void*)l, 16, 0, 0);
}
__device__ __forceinline__ u16 f2b(float v) {
    __hip_bfloat16 h = __float2bfloat16(v);
    return *reinterpret_cast<u16*>(&h);
}
__device__ __forceinline__ float ternq(float x, float d) {
    return (fabsf(x) > d) ? (x > 0.f ? 1.f : -1.f) : 0.f;
}

// ---------------- ws layout (BYTE offsets) ----------------
constexpr size_t ALGN(size_t x) { return (x + 255) & ~(size_t)255; }
constexpr size_t O_SUMS = 0;                                   // 8 f32
constexpr size_t O_W1R  = 256;                                 // 288 f32
constexpr size_t O_WF2Q = ALGN(O_W1R + 288 * 4);               // 32768 f32
constexpr size_t O_WF3Q = ALGN(O_WF2Q + 32768 * 4);            // 1280 f32
constexpr size_t O_BQ2  = ALGN(O_WF3Q + 1280 * 4);             // [64][288] bf16
constexpr size_t O_BQ3  = ALGN(O_BQ2 + 64 * 288 * 2);          // [128][576] bf16
constexpr size_t O_BQ4  = ALGN(O_BQ3 + 128 * 576 * 2);         // [128][1152] bf16
constexpr size_t O_BQF1 = ALGN(O_BQ4 + 128 * 1152 * 2);        // [256][6272] bf16
constexpr size_t O_F1   = ALGN(O_BQF1 + (size_t)256 * 6272 * 2);  // [1024][256] f32
constexpr size_t O_F2   = ALGN(O_F1 + 1024 * 256 * 4);         // [1024][128] f32
constexpr size_t O_ACT1 = ALGN(O_F2 + 1024 * 128 * 4);         // pad30 C=32 bf16: 1024*900*32
constexpr size_t O_ACT2 = ALGN(O_ACT1 + (size_t)1024 * 900 * 32 * 2);  // pad16 C=64
constexpr size_t O_ACT3 = ALGN(O_ACT2 + (size_t)1024 * 256 * 64 * 2);  // pad16 C=128
constexpr size_t O_ACT4 = ALGN(O_ACT3 + (size_t)1024 * 256 * 128 * 2); // [1024*49][128]
// total ~185 MB

// ---------------- ternarization (merged) ----------------
__global__ void zero_sums(float* s) { if (threadIdx.x < 8) s[threadIdx.x] = 0.f; }

__device__ void absmean_seg(const float* __restrict__ w, int n4, float* __restrict__ sum,
                            int b0, int nb) {
    __shared__ float sm[256];
    float s = 0.f;
    for (int i = b0 * 256 + threadIdx.x; i < n4; i += nb * 256) {
        float4 v = ((const float4*)w)[i];
        s += fabsf(v.x) + fabsf(v.y) + fabsf(v.z) + fabsf(v.w);
    }
    sm[threadIdx.x] = s;
    __syncthreads();
    for (int o = 128; o > 0; o >>= 1) {
        if (threadIdx.x < o) sm[threadIdx.x] += sm[threadIdx.x + o];
        __syncthreads();
    }
    if (threadIdx.x == 0) atomicAdd(sum, sm[0]);
}

__global__ void absmean_all(const float* w1, const float* w2, const float* w3, const float* w4,
                            const float* wf1, const float* wf2, const float* wf3, float* sums) {
    int b = blockIdx.x;
    if (b < 160)      absmean_seg(wf1, 401408, sums + 4, b, 160);
    else if (b < 192) absmean_seg(w4, 36864, sums + 3, b - 160, 32);
    else if (b < 208) absmean_seg(w3, 18432, sums + 2, b - 192, 16);
    else if (b < 216) absmean_seg(w2, 4608, sums + 1, b - 208, 8);
    else if (b < 224) absmean_seg(wf2, 8192, sums + 5, b - 216, 8);
    else if (b < 225) absmean_seg(w1, 72, sums + 0, 0, 1);
    else              absmean_seg(wf3, 320, sums + 6, 0, 1);
}

__device__ void tern_conv_seg(const float* __restrict__ w, float d, u16* __restrict__ bq,
                              int COUT, int CIN, int b0, int nb) {
    int N = COUT * CIN * 9;
    for (int i = b0 * 256 + threadIdx.x; i < N; i += nb * 256) {
        float q = ternq(w[i], d);
        int co = i / (CIN * 9), r = i % (CIN * 9);
        int ci = r / 9, tap = r % 9;
        bq[(size_t)co * CIN * 9 + tap * CIN + ci] = f2b(q);
    }
}
__device__ void tern_f32_seg(const float* __restrict__ w, float d, float* __restrict__ wq,
                             int N, int b0, int nb) {
    for (int i = b0 * 256 + threadIdx.x; i < N; i += nb * 256) wq[i] = ternq(w[i], d);
}

__global__ void tern_all(const float* w1, const float* w2, const float* w3, const float* w4,
                         const float* wf1, const float* wf2, const float* wf3,
                         const float* __restrict__ sums,
                         float* w1r, u16* bq2, u16* bq3, u16* bq4, u16* bqf1,
                         float* wf2q, float* wf3q) {
    int b = blockIdx.x;
    if (b < 1) {
        tern_f32_seg(w1, 0.7f * sums[0] / 288.f, w1r, 288, 0, 1);
    } else if (b < 9) {
        tern_conv_seg(w2, 0.7f * sums[1] / 18432.f, bq2, 64, 32, b - 1, 8);
    } else if (b < 41) {
        tern_conv_seg(w3, 0.7f * sums[2] / 73728.f, bq3, 128, 64, b - 9, 32);
    } else if (b < 105) {
        tern_conv_seg(w4, 0.7f * sums[3] / 147456.f, bq4, 128, 128, b - 41, 64);
    } else if (b < 617) {
        // wf1 [256][6272], k=c*49+s -> bf16 [256][s*128+c]
        float d = 0.7f * sums[4] / 1605632.f;
        for (int i = (b - 105) * 256 + threadIdx.x; i < 1605632; i += 512 * 256) {
            float q = ternq(wf1[i], d);
            int j = i / 6272, k = i % 6272;
            int c = k / 49, s = k % 49;
            bqf1[(size_t)j * 6272 + s * 128 + c] = f2b(q);
        }
    } else if (b < 633) {
        tern_f32_seg(wf2, 0.7f * sums[5] / 32768.f, wf2q, 32768, b - 617, 16);
    } else {
        tern_f32_seg(wf3, 0.7f * sums[6] / 1280.f, wf3q, 1280, 0, 1);
    }
}

__global__ void zero_f1(float* f1) {
    ((float4*)f1)[blockIdx.x * 256 + threadIdx.x] = make_float4(0.f, 0.f, 0.f, 0.f);
}

// ---------------- conv1 direct (Cin=1) -> pad30 NHWC bf16 ----------------
__global__ __launch_bounds__(256)
void conv1_direct(const float* __restrict__ x, const float* __restrict__ w1r,
                  const float* __restrict__ bias, const float* __restrict__ gam,
                  const float* __restrict__ bet, const float* __restrict__ mu,
                  const float* __restrict__ var, u16* __restrict__ out) {
    __shared__ float xs[784];
    __shared__ float wsh[288];
    __shared__ float scl[32], sft[32];
    const int n = blockIdx.x, tid = threadIdx.x;
    for (int i = tid; i < 784; i += 256) xs[i] = x[(size_t)n * 784 + i];
    for (int i = tid; i < 288; i += 256) wsh[i] = w1r[i];
    if (tid < 32) {
        float s = gam[tid] * rsqrtf(var[tid] + BN_EPS);
        scl[tid] = s;
        sft[tid] = (bias[tid] - mu[tid]) * s + bet[tid];
    }
    __syncthreads();
    for (int p = tid; p < 784; p += 256) {
        int y = p / 28, xx = p % 28;
        float patch[9];
#pragma unroll
        for (int dy = 0; dy < 3; ++dy)
#pragma unroll
            for (int dx = 0; dx < 3; ++dx) {
                int gy = y + dy - 1, gx = xx + dx - 1;
                patch[dy * 3 + dx] = (gy >= 0 && gy < 28 && gx >= 0 && gx < 28) ? xs[gy * 28 + gx] : 0.f;
            }
        u32 pk[16];
#pragma unroll
        for (int co = 0; co < 32; co += 2) {
            float s0 = 0.f, s1 = 0.f;
#pragma unroll
            for (int t = 0; t < 9; ++t) {
                s0 += wsh[co * 9 + t] * patch[t];
                s1 += wsh[(co + 1) * 9 + t] * patch[t];
            }
            float v0 = fmaxf(s0 * scl[co] + sft[co], 0.f);
            float v1 = fmaxf(s1 * scl[co + 1] + sft[co + 1], 0.f);
            pk[co >> 1] = ((u32)f2b(v1) << 16) | (u32)f2b(v0);
        }
        size_t base = ((size_t)(n * 30 + y + 1) * 30 + (xx + 1)) * 32;
#pragma unroll
        for (int q = 0; q < 4; ++q) ((uint4*)(out + base))[q] = ((uint4*)pk)[q];
    }
}

// ---------------- border zero for padded NHWC buffers ----------------
template<int C, int HP, int HV>
__global__ void border_zero(u16* __restrict__ buf) {
    constexpr int NB = 2 * HP + 2 * HV;
    constexpr int CG = C / 8;
    int i = blockIdx.x * blockDim.x + threadIdx.x;
    if (i >= 1024 * NB * CG) return;
    int cg = i % CG, r = i / CG;
    int b = r % NB, n = r / NB;
    int py, px;
    if (b < HP)               { py = 0;                  px = b; }
    else if (b < 2 * HP)      { py = HP - 1;             px = b - HP; }
    else if (b < 2 * HP + HV) { py = b - 2 * HP + 1;     px = 0; }
    else                      { py = b - 2 * HP - HV + 1; px = HP - 1; }
    size_t off = ((size_t)(n * HP + py) * HP + px) * C + cg * 8;
    *(uint4*)(buf + off) = make_uint4(0, 0, 0, 0);
}

// ---------------- implicit-GEMM conv, bf16 MFMA, fragment-major LDS ----------------
// A: NHWC padded in act[n][HP][HP][CIN]; B: bq[co][tap*CIN+ci]
// BM=128; BK=32*G per barrier; pool fused via quad-row m-mapping when POOL.
// LDS frag-major: kgroup j region = [rowgroup(BM/16)][chunk(4)][row16][16B];
// wave frag read = base + lane*16 (conflict-free).
template<int CIN, int BN, int HV, int HP, int G, bool POOL, bool PADOUT>
__global__ __launch_bounds__(256)
void convgemm(const u16* __restrict__ act, const u16* __restrict__ bq,
              const float* __restrict__ bias, const float* __restrict__ gam,
              const float* __restrict__ bet, const float* __restrict__ mu,
              const float* __restrict__ var, u16* __restrict__ out) {
    constexpr int BM = 128;
    constexpr int K = 9 * CIN;
    constexpr int S = K / (32 * G);
    constexpr int TPC = CIN / 32;     // kgroups per tap
    constexpr int NT = BN / 32;       // per-wave n-tiles (2 or 4)
    constexpr int RB = BN / 64;       // B staging rounds per kgroup
    constexpr int HO = HV / 2;
    constexpr int PP = POOL ? HO * HO : HV * HV;

    __shared__ __align__(16) u16 Alds[G][BM * 32];
    __shared__ __align__(16) u16 Blds[G][BN * 32];
    __shared__ int rowA[BM];
    __shared__ int rowO[BM];
    __shared__ float scl[BN], sft[BN];

    const int tid = threadIdx.x;
    const int m0 = blockIdx.x * BM;

    for (int t = tid; t < BM; t += 256) {
        int base;
        if (POOL) {
            int p = (m0 >> 2) + (t >> 2), q = t & 3;
            int n = p / PP, rr = p % PP;
            int oy = rr / HO, ox = rr % HO;
            int y = oy * 2 + (q >> 1), x = ox * 2 + (q & 1);
            base = ((n * HP + y) * HP + x) * CIN;
        } else {
            int m = m0 + t;
            int n = m / PP, rr = m % PP;
            int y = rr / HV, x = rr % HV;
            base = ((n * HP + y) * HP + x) * CIN;
        }
        rowA[t] = base;
    }
    if (POOL) {
        if (tid < 32) {
            int p = (m0 >> 2) + tid;
            int n = p / PP, rr = p % PP;
            int oy = rr / HO, ox = rr % HO;
            rowO[tid] = PADOUT ? ((n * 16 + oy + 1) * 16 + ox + 1) * BN : p * BN;
        }
    } else {
        for (int t = tid; t < BM; t += 256) {
            int m = m0 + t;
            int n = m / PP, rr = m % PP;
            int y = rr / HV, x = rr % HV;
            rowO[t] = PADOUT ? ((n * 16 + y + 1) * 16 + x + 1) * BN : m * BN;
        }
    }
    if (tid < BN) {
        float s = gam[tid] * rsqrtf(var[tid] + BN_EPS);
        scl[tid] = s;
        sft[tid] = (bias[tid] - mu[tid]) * s + bet[tid];
    }
    __syncthreads();

    int arow[2];
    arow[0] = rowA[(tid >> 6) * 16 + (tid & 15)];
    arow[1] = rowA[64 + (tid >> 6) * 16 + (tid & 15)];
    const int chunkb = ((tid >> 4) & 3) * 16;
    const int bco = (tid >> 6) * 16 + (tid & 15);
    const char* actb = (const char*)act;
    const char* bqb  = (const char*)bq;

    const int wave = tid >> 6, lane = tid & 63;
    const int wm = wave & 1, wn = wave >> 1;
    const int fr16 = lane * 16;

    f32x4 acc[4][NT] = {};

    for (int s = 0; s < S; ++s) {
#pragma unroll
        for (int j = 0; j < G; ++j) {
            int g = s * G + j;
            int tap = g / TPC, cio = (g % TPC) * 32;
            int dy = tap / 3, dx = tap % 3;
            int toffb = ((dy * HP + dx) * CIN + cio) * 2;
            char* Al = (char*)Alds[j];
#pragma unroll
            for (int r = 0; r < 2; ++r)
                load16(actb + (size_t)arow[r] * 2 + toffb + chunkb, Al + r * 4096 + tid * 16);
            char* Bl = (char*)Blds[j];
            int bkob = g * 64 + chunkb;
#pragma unroll
            for (int r = 0; r < RB; ++r)
                load16(bqb + (size_t)(r * 64 + bco) * K * 2 + bkob, Bl + r * 4096 + tid * 16);
        }
        __syncthreads();
#pragma unroll
        for (int j = 0; j < G; ++j) {
            const char* Al = (const char*)Alds[j];
            const char* Bl = (const char*)Blds[j];
            bf16x8 af[4], bf[NT];
#pragma unroll
            for (int mt = 0; mt < 4; ++mt)
                af[mt] = *(const bf16x8*)(Al + (wm * 4 + mt) * 1024 + fr16);
#pragma unroll
            for (int nt = 0; nt < NT; ++nt)
                bf[nt] = *(const bf16x8*)(Bl + (wn * NT + nt) * 1024 + fr16);
#pragma unroll
            for (int mt = 0; mt < 4; ++mt)
#pragma unroll
                for (int nt = 0; nt < NT; ++nt)
                    acc[mt][nt] = __builtin_amdgcn_mfma_f32_16x16x32_bf16(af[mt], bf[nt], acc[mt][nt], 0, 0, 0);
        }
        __syncthreads();
    }

    const int fr = lane & 15, quad = lane >> 4;
    if (POOL) {
#pragma unroll
        for (int mt = 0; mt < 4; ++mt) {
            int pl = wm * 16 + mt * 4 + quad;
            int ob = rowO[pl];
#pragma unroll
            for (int nt = 0; nt < NT; ++nt) {
                int col = wn * (NT * 16) + nt * 16 + fr;
                float sc = scl[col], sh = sft[col];
                f32x4 a = acc[mt][nt];
                float v0 = a[0] * sc + sh, v1 = a[1] * sc + sh;
                float v2 = a[2] * sc + sh, v3 = a[3] * sc + sh;
                float mx = fmaxf(fmaxf(v0, v1), fmaxf(v2, v3));
                out[(size_t)ob + col] = f2b(fmaxf(mx, 0.f));
            }
        }
    } else {
#pragma unroll
        for (int mt = 0; mt < 4; ++mt) {
            int rb = wm * 64 + mt * 16 + quad * 4;
            int o0 = rowO[rb], o1 = rowO[rb + 1], o2 = rowO[rb + 2], o3 = rowO[rb + 3];
#pragma unroll
            for (int nt = 0; nt < NT; ++nt) {
                int col = wn * (NT * 16) + nt * 16 + fr;
                float sc = scl[col], sh = sft[col];
                f32x4 a = acc[mt][nt];
                out[(size_t)o0 + col] = f2b(fmaxf(a[0] * sc + sh, 0.f));
                out[(size_t)o1 + col] = f2b(fmaxf(a[1] * sc + sh, 0.f));
                out[(size_t)o2 + col] = f2b(fmaxf(a[2] * sc + sh, 0.f));
                out[(size_t)o3 + col] = f2b(fmaxf(a[3] * sc + sh, 0.f));
            }
        }
    }
}

// ---------------- fc1: split-K MFMA GEMM, atomicAdd f32 partials into f1 ----------------
__global__ __launch_bounds__(256)
void fc1gemm(const u16* __restrict__ A, const u16* __restrict__ Bq, float* __restrict__ out) {
    constexpr int K = 6272, KC = 896, S = KC / 64;
    __shared__ __align__(16) u16 Alds[2][128 * 32];
    __shared__ __align__(16) u16 Blds[2][128 * 32];
    const int tid = threadIdx.x;
    const int m0 = blockIdx.x * 128;
    const int n0 = blockIdx.y * 128;
    const int k0 = blockIdx.z * KC;
    const int chunkb = ((tid >> 4) & 3) * 16;
    const int rr = (tid >> 6) * 16 + (tid & 15);
    const char* Ag = (const char*)A;
    const char* Bg = (const char*)Bq;
    const int wave = tid >> 6, lane = tid & 63;
    const int wm = wave & 1, wn = wave >> 1;
    const int fr16 = lane * 16;
    f32x4 acc[4][4] = {};

    for (int s = 0; s < S; ++s) {
#pragma unroll
        for (int j = 0; j < 2; ++j) {
            int kb = (k0 + s * 64 + j * 32) * 2 + chunkb;
            char* Al = (char*)Alds[j];
            char* Bl = (char*)Blds[j];
#pragma unroll
            for (int r = 0; r < 2; ++r) {
                load16(Ag + (size_t)(m0 + r * 64 + rr) * K * 2 + kb, Al + r * 4096 + tid * 16);
                load16(Bg + (size_t)(n0 + r * 64 + rr) * K * 2 + kb, Bl + r * 4096 + tid * 16);
            }
        }
        __syncthreads();
#pragma unroll
        for (int j = 0; j < 2; ++j) {
            const char* Al = (const char*)Alds[j];
            const char* Bl = (const char*)Blds[j];
            bf16x8 af[4], bf[4];
#pragma unroll
            for (int mt = 0; mt < 4; ++mt)
                af[mt] = *(const bf16x8*)(Al + (wm * 4 + mt) * 1024 + fr16);
#pragma unroll
            for (int nt = 0; nt < 4; ++nt)
                bf[nt] = *(const bf16x8*)(Bl + (wn * 4 + nt) * 1024 + fr16);
#pragma unroll
            for (int mt = 0; mt < 4; ++mt)
#pragma unroll
                for (int nt = 0; nt < 4; ++nt)
                    acc[mt][nt] = __builtin_amdgcn_mfma_f32_16x16x32_bf16(af[mt], bf[nt], acc[mt][nt], 0, 0, 0);
        }
        __syncthreads();
    }
    const int fr = lane & 15, quad = lane >> 4;
#pragma unroll
    for (int mt = 0; mt < 4; ++mt) {
        int row = m0 + wm * 64 + mt * 16 + quad * 4;
#pragma unroll
        for (int nt = 0; nt < 4; ++nt) {
            int col = n0 + wn * 64 + nt * 16 + fr;
            f32x4 a = acc[mt][nt];
            atomicAdd(&out[(size_t)(row + 0) * 256 + col], a[0]);
            atomicAdd(&out[(size_t)(row + 1) * 256 + col], a[1]);
            atomicAdd(&out[(size_t)(row + 2) * 256 + col], a[2]);
            atomicAdd(&out[(size_t)(row + 3) * 256 + col], a[3]);
        }
    }
}

// ---------------- fc2 fp32 GEMM; applies fc1's BN+ReLU to A on load ----------------
__global__ __launch_bounds__(256)
void fc2_kernel(const float* __restrict__ A, const float* __restrict__ Bw,
                const float* __restrict__ bA, const float* __restrict__ gA,
                const float* __restrict__ beA, const float* __restrict__ mA,
                const float* __restrict__ vA,
                const float* __restrict__ bias, const float* __restrict__ gam,
                const float* __restrict__ bet, const float* __restrict__ mu,
                const float* __restrict__ var, float* __restrict__ out) {
    constexpr int M = 1024, Nn = 128, K = 256;
    __shared__ __align__(16) float As[16][68];
    __shared__ __align__(16) float Bs[16][68];
    __shared__ float sclA[256], sftA[256];
    const int tid = threadIdx.x;
    const int n0 = blockIdx.x * 64, m0 = blockIdx.y * 64;
    if (tid < 256) {
        float s = gA[tid] * rsqrtf(vA[tid] + BN_EPS);
        sclA[tid] = s;
        sftA[tid] = (bA[tid] - mA[tid]) * s + beA[tid];
    }
    const int tm = tid >> 4, tn = tid & 15;
    const int lr = tid >> 2, lk = (tid & 3) * 4;
    float acc[4][4] = {};
    __syncthreads();
    for (int k0 = 0; k0 < K; k0 += 16) {
        float4 av = *(const float4*)&A[(size_t)(m0 + lr) * K + k0 + lk];
        float4 bv = *(const float4*)&Bw[(size_t)(n0 + lr) * K + k0 + lk];
        As[lk + 0][lr] = fmaxf(av.x * sclA[k0 + lk + 0] + sftA[k0 + lk + 0], 0.f);
        As[lk + 1][lr] = fmaxf(av.y * sclA[k0 + lk + 1] + sftA[k0 + lk + 1], 0.f);
        As[lk + 2][lr] = fmaxf(av.z * sclA[k0 + lk + 2] + sftA[k0 + lk + 2], 0.f);
        As[lk + 3][lr] = fmaxf(av.w * sclA[k0 + lk + 3] + sftA[k0 + lk + 3], 0.f);
        Bs[lk + 0][lr] = bv.x; Bs[lk + 1][lr] = bv.y; Bs[lk + 2][lr] = bv.z; Bs[lk + 3][lr] = bv.w;
        __syncthreads();
#pragma unroll
        for (int k = 0; k < 16; ++k) {
            float4 a = *(const float4*)&As[k][tm * 4];
            float4 b = *(const float4*)&Bs[k][tn * 4];
            acc[0][0] += a.x * b.x; acc[0][1] += a.x * b.y; acc[0][2] += a.x * b.z; acc[0][3] += a.x * b.w;
            acc[1][0] += a.y * b.x; acc[1][1] += a.y * b.y; acc[1][2] += a.y * b.z; acc[1][3] += a.y * b.w;
            acc[2][0] += a.z * b.x; acc[2][1] += a.z * b.y; acc[2][2] += a.z * b.z; acc[2][3] += a.z * b.w;
            acc[3][0] += a.w * b.x; acc[3][1] += a.w * b.y; acc[3][2] += a.w * b.z; acc[3][3] += a.w * b.w;
        }
        __syncthreads();
    }
#pragma unroll
    for (int i = 0; i < 4; ++i) {
        int row = m0 + tm * 4 + i;
#pragma unroll
        for (int j = 0; j < 4; ++j) {
            int col = n0 + tn * 4 + j;
            float sc = gam[col] * rsqrtf(var[col] + BN_EPS);
            float v = (acc[i][j] + bias[col] - mu[col]) * sc + bet[col];
            out[(size_t)row * Nn + col] = fmaxf(v, 0.f);
        }
    }
}

__global__ __launch_bounds__(256)
void fc3_kernel(const float* __restrict__ A, const float* __restrict__ Bw,
                const float* __restrict__ bias, float* __restrict__ out) {
    int i = blockIdx.x * blockDim.x + threadIdx.x;
    if (i >= 1024 * 10) return;
    int n = i / 10, j = i % 10;
    const float4* a = (const float4*)&A[(size_t)n * 128];
    const float4* b = (const float4*)&Bw[(size_t)j * 128];
    float s = 0.f;
#pragma unroll
    for (int k = 0; k < 32; ++k) {
        float4 x = a[k], y = b[k];
        s += x.x * y.x + x.y * y.y + x.z * y.z + x.w * y.w;
    }
    out[i] = s + bias[j];
}

extern "C" void kernel_launch(void* const* d_in, const int* in_sizes, int n_in,
                              void* d_out, int out_size, void* d_ws, size_t ws_size,
                              hipStream_t stream) {
    (void)in_sizes; (void)n_in; (void)out_size; (void)ws_size;
    const float* x   = (const float*)d_in[0];
    const float* w1  = (const float*)d_in[1];
    const float* w2  = (const float*)d_in[2];
    const float* w3  = (const float*)d_in[3];
    const float* w4  = (const float*)d_in[4];
    const float* wf1 = (const float*)d_in[5];
    const float* wf2 = (const float*)d_in[6];
    const float* wf3 = (const float*)d_in[7];
    auto P = [&](int i) { return (const float*)d_in[i]; };
    char* wsb = (char*)d_ws;
    float* sums = (float*)(wsb + O_SUMS);
    float* w1r  = (float*)(wsb + O_W1R);
    float* wf2q = (float*)(wsb + O_WF2Q);
    float* wf3q = (float*)(wsb + O_WF3Q);
    u16* bq2   = (u16*)(wsb + O_BQ2);
    u16* bq3   = (u16*)(wsb + O_BQ3);
    u16* bq4   = (u16*)(wsb + O_BQ4);
    u16* bqf1  = (u16*)(wsb + O_BQF1);
    float* f1  = (float*)(wsb + O_F1);
    float* f2  = (float*)(wsb + O_F2);
    u16* act1  = (u16*)(wsb + O_ACT1);
    u16* act2p = (u16*)(wsb + O_ACT2);
    u16* act3  = (u16*)(wsb + O_ACT3);
    u16* act4p = (u16*)(wsb + O_ACT4);

    // ternarization: 3 launches
    zero_sums<<<1, 64, 0, stream>>>(sums);
    absmean_all<<<226, 256, 0, stream>>>(w1, w2, w3, w4, wf1, wf2, wf3, sums);
    tern_all<<<634, 256, 0, stream>>>(w1, w2, w3, w4, wf1, wf2, wf3, sums,
                                      w1r, bq2, bq3, bq4, bqf1, wf2q, wf3q);

    // border zeros + f1 zero (independent)
    border_zero<32, 30, 28><<<(1024 * 116 * 4 + 255) / 256, 256, 0, stream>>>(act1);
    border_zero<64, 16, 14><<<(1024 * 60 * 8 + 255) / 256, 256, 0, stream>>>(act2p);
    border_zero<128, 16, 14><<<(1024 * 60 * 16 + 255) / 256, 256, 0, stream>>>(act3);
    zero_f1<<<256, 256, 0, stream>>>(f1);

    // conv1 -> act1 (pad30 interior)
    conv1_direct<<<1024, 256, 0, stream>>>(x, w1r, P(8), P(9), P(10), P(11), P(12), act1);
    // conv2 + fused pool -> act2p (pad16 C=64 interior); M=802816, G=3
    convgemm<32, 64, 28, 30, 3, true, true><<<6272, 256, 0, stream>>>(
        act1, bq2, P(13), P(14), P(15), P(16), P(17), act2p);
    // conv3 -> act3 (pad16 C=128 interior); M=200704, G=2
    convgemm<64, 128, 14, 16, 2, false, true><<<1568, 256, 0, stream>>>(
        act2p, bq3, P(18), P(19), P(20), P(21), P(22), act3);
    // conv4 + fused pool -> act4p flat [1024*49][128]; M=200704, G=2
    convgemm<128, 128, 14, 16, 2, true, false><<<1568, 256, 0, stream>>>(
        act3, bq4, P(23), P(24), P(25), P(26), P(27), act4p);
    // fc1 split-K (7 chunks of 896) -> atomic f32 into f1
    fc1gemm<<<dim3(8, 2, 7), 256, 0, stream>>>(act4p, bqf1, f1);
    // fc2 (applies fc1 BN+ReLU on A-load) -> f2
    fc2_kernel<<<dim3(2, 16), 256, 0, stream>>>(
        f1, wf2q, P(28), P(29), P(30), P(31), P(32),
        P(33), P(34), P(35), P(36), P(37), f2);
    // fc3 -> logits
    fc3_kernel<<<40, 256, 0, stream>>>(f2, wf3q, P(38), (float*)d_out);
}